// Round 4
// baseline (365.454 us; speedup 1.0000x reference)
//
#include <hip/hip_runtime.h>
#include <hip/hip_fp16.h>
#include <stdint.h>

// Problem dims (fixed by reference)
// Reference dtypes: x fp16, bias fp16, out fp16 -> harness passes/reads FLOAT32.
// packed_w int32 (8192 x 512), 16 two-bit codes per word, values {0,1,3}.
#define M_DIM 1024
#define N_DIM 8192
#define K_DIM 8192
#define KP    (K_DIM / 16)   // 512 packed int32 words per weight row

// Tiling (m97-family structure: 128x128 tile, BK=64, 2x2 waves of 64x64)
#define BM 128
#define BN 128
#define BK 64
#define NTHREADS 256
#define LDS_STRIDE 144        // 64 fp16 (128 B) + 16 B pad; stride/4 = 36 banks ->
                              // b128 fragment reads are 2-way conflicts (free, m136)

typedef _Float16 half8  __attribute__((ext_vector_type(8)));
typedef __fp16   fp16x2 __attribute__((ext_vector_type(2)));  // cvt_pkrtz return type
typedef float    f32x4  __attribute__((ext_vector_type(4)));

// 2-bit code -> fp16 bits. Codes {0,1,3} -> 0x0000 / 0x3C00 / 0x4200 (0.0 / 1.0 / 3.0).
// val16(c) = (c&1)*0x3C00 + (c>>1)*0x0600
__device__ __forceinline__ uint32_t unpack_pair16(uint32_t u, int p) {
  uint32_t c0 = (u >> (4 * p)) & 3u;
  uint32_t c1 = (u >> (4 * p + 2)) & 3u;
  uint32_t lo = (c0 & 1u) * 0x3C00u + (c0 >> 1) * 0x0600u;
  uint32_t hi = (c1 & 1u) * 0x3C00u + (c1 >> 1) * 0x0600u;
  return lo | (hi << 16);
}

__device__ __forceinline__ uint32_t cvt2(float a, float b) {
  fp16x2 p = __builtin_amdgcn_cvt_pkrtz(a, b);   // RTZ exact: values are fp16-representable
  return __builtin_bit_cast(uint32_t, p);
}

__global__ __launch_bounds__(NTHREADS, 2)
void ternary_gemm(const float* __restrict__ x,
                  const int*   __restrict__ pw,
                  const float* __restrict__ bias,
                  float*       __restrict__ out) {
  __shared__ __align__(16) char AsB[BM * LDS_STRIDE];  // 18432 B (fp16 tile)
  __shared__ __align__(16) char BsB[BN * LDS_STRIDE];  // 18432 B

  const int tid  = threadIdx.x;
  const int lane = tid & 63;
  const int w    = tid >> 6;
  const int wm   = w >> 1;          // wave row (0..1)
  const int wn   = w & 1;           // wave col (0..1)

  // XCD-friendly flat swizzle: bid%8 -> bm (8 m-tiles), bid>>3 -> bn (64 n-tiles)
  const int bid = blockIdx.x;
  const int bm  = (bid & 7) * BM;
  const int bn  = (bid >> 3) * BN;

  // ---- A staging: thread t -> row t>>1 (0..127), k-half t&1 (32 f32 = 128 B) ----
  const int rT = tid >> 1;          // row 0..127 (shared by A and B staging)
  const int hT = tid & 1;
  const float* gA = x + (size_t)(bm + rT) * K_DIM + hT * 32;
  char* const  lA = AsB + rT * LDS_STRIDE + hT * 64;   // 32 fp16 = 64 B

  // ---- B staging: thread t -> row t>>1, packed words (t&1)*2 .. +1 per K-tile ----
  const int2* gB = (const int2*)pw + (size_t)(bn + rT) * (KP / 2) + hT;
  char* dBp[4];
#pragma unroll
  for (int h = 0; h < 4; ++h)
    dBp[h] = BsB + rT * LDS_STRIDE + (hT * 4 + h) * 16;

  // ---- fragment read offsets (kt-invariant) ----
  // A operand: lane holds A[m = lane&15][k = (lane>>4)*8 + j]
  // B operand: lane holds W[n = lane&15][k = (lane>>4)*8 + j]   (B^T row-major)
  int offA[4][2], offB[4][2];
#pragma unroll
  for (int i = 0; i < 4; ++i) {
#pragma unroll
    for (int ks = 0; ks < 2; ++ks) {
      int c = ks * 4 + (lane >> 4);
      offA[i][ks] = (wm * 64 + i * 16 + (lane & 15)) * LDS_STRIDE + c * 16;
      offB[i][ks] = (wn * 64 + i * 16 + (lane & 15)) * LDS_STRIDE + c * 16;
    }
  }

  f32x4 acc[4][4];
#pragma unroll
  for (int i = 0; i < 4; ++i)
#pragma unroll
    for (int j = 0; j < 4; ++j)
      acc[i][j] = (f32x4){0.f, 0.f, 0.f, 0.f};

  const int NT = K_DIM / BK;        // 128 K-tiles

  for (int kt = 0; kt < NT; ++kt) {
    __syncthreads();                // all waves done reading previous tile

    // Issue all global loads up front (B first; 9 loads in flight together)
    int2 wcur = gB[kt * 2];
    float4 av[8];
#pragma unroll
    for (int v = 0; v < 8; ++v)
      av[v] = *(const float4*)(gA + kt * BK + v * 4);

    // B unpack (depends only on wcur; VALU overlaps remaining A-load latency)
    uint32_t d0[8], d1[8];
#pragma unroll
    for (int p = 0; p < 8; ++p) d0[p] = unpack_pair16((uint32_t)wcur.x, p);
#pragma unroll
    for (int p = 0; p < 8; ++p) d1[p] = unpack_pair16((uint32_t)wcur.y, p);
    *(uint4*)dBp[0] = make_uint4(d0[0], d0[1], d0[2], d0[3]);
    *(uint4*)dBp[1] = make_uint4(d0[4], d0[5], d0[6], d0[7]);
    *(uint4*)dBp[2] = make_uint4(d1[0], d1[1], d1[2], d1[3]);
    *(uint4*)dBp[3] = make_uint4(d1[4], d1[5], d1[6], d1[7]);

    // A: f32 -> fp16, 4 x b128 LDS writes
#pragma unroll
    for (int v = 0; v < 4; ++v) {
      uint4 aw;
      aw.x = cvt2(av[2 * v].x, av[2 * v].y);
      aw.y = cvt2(av[2 * v].z, av[2 * v].w);
      aw.z = cvt2(av[2 * v + 1].x, av[2 * v + 1].y);
      aw.w = cvt2(av[2 * v + 1].z, av[2 * v + 1].w);
      *(uint4*)(lA + v * 16) = aw;
    }

    __syncthreads();                // staging visible to all waves

#pragma unroll
    for (int ks = 0; ks < 2; ++ks) {
      half8 af[4], bf[4];
#pragma unroll
      for (int i = 0; i < 4; ++i) af[i] = *(const half8*)(AsB + offA[i][ks]);
#pragma unroll
      for (int j = 0; j < 4; ++j) bf[j] = *(const half8*)(BsB + offB[j][ks]);
#pragma unroll
      for (int i = 0; i < 4; ++i)
#pragma unroll
        for (int j = 0; j < 4; ++j)
          acc[i][j] = __builtin_amdgcn_mfma_f32_16x16x32_f16(af[i], bf[j], acc[i][j], 0, 0, 0);
    }
  }

  // Epilogue: D layout col(n) = lane&15, row(m) = (lane>>4)*4 + reg  [m89/m91]
  // Replicate reference rounding exactly: fp16(y) + fp16(bias) in half, widen to f32.
#pragma unroll
  for (int j = 0; j < 4; ++j) {
    int n = bn + wn * 64 + j * 16 + (lane & 15);
    __half hb = __float2half_rn(bias[n]);   // exact round-trip (bias was fp16)
#pragma unroll
    for (int i = 0; i < 4; ++i) {
      int m0 = bm + wm * 64 + i * 16 + (lane >> 4) * 4;
#pragma unroll
      for (int r = 0; r < 4; ++r) {
        __half hy = __float2half_rn(acc[i][j][r]);
        float v = __half2float(__hadd(hy, hb));
        out[(size_t)(m0 + r) * N_DIM + n] = v;
      }
    }
  }
}

extern "C" void kernel_launch(void* const* d_in, const int* in_sizes, int n_in,
                              void* d_out, int out_size, void* d_ws, size_t ws_size,
                              hipStream_t stream) {
  (void)in_sizes; (void)n_in; (void)out_size; (void)d_ws; (void)ws_size;
  const float* x    = (const float*)d_in[0];
  const int*   pwp  = (const int*)d_in[1];
  const float* bias = (const float*)d_in[2];
  float*       outp = (float*)d_out;

  dim3 grid((M_DIM / BM) * (N_DIM / BN));  // 512 blocks
  ternary_gemm<<<grid, NTHREADS, 0, stream>>>(x, pwp, bias, outp);
}

// Round 5
// 243.240 us; speedup vs baseline: 1.5024x; 1.5024x over previous
//
#include <hip/hip_runtime.h>
#include <hip/hip_fp16.h>
#include <stdint.h>

// Problem dims (fixed by reference)
// Reference dtypes: x fp16, bias fp16, out fp16 -> harness passes/reads FLOAT32.
// packed_w int32 (8192 x 512), 16 two-bit codes per word, values {0,1,3}.
#define M_DIM 1024
#define N_DIM 8192
#define K_DIM 8192
#define KP    (K_DIM / 16)   // 512 packed int32 words per weight row

#define BM 128
#define BN 128
#define BK 64
#define NTHREADS 256
#define A_STRIDE 128          // fp16 A tile row: 64*2 B, unpadded (global_load_lds), XOR-swizzled
#define B_STRIDE 144          // fp16 B tile row: 128 B + 16 pad (36 banks -> 2-way = free)

typedef _Float16 half8  __attribute__((ext_vector_type(8)));
typedef __fp16   fp16x2 __attribute__((ext_vector_type(2)));
typedef float    f32x4  __attribute__((ext_vector_type(4)));

#define AS1(p) ((const __attribute__((address_space(1))) void*)(p))
#define AS3(p) ((__attribute__((address_space(3))) void*)(p))

__device__ __forceinline__ uint32_t cvt2(float a, float b) {
  fp16x2 p = __builtin_amdgcn_cvt_pkrtz(a, b);   // RTZ exact: values are fp16-representable
  return __builtin_bit_cast(uint32_t, p);
}

// ---- v_perm ternary decode ----
// fp16 of {0,1,2,3} = 0x0000/0x3C00/0x0600?/0x4200 -- low byte always 0x00, so one
// table byte per code: T = bytes[0x00, 0x3C, 0x06, 0x42] (code 2 unused by format).
// Sel spread: byte b of u holds codes c0..c3 (2 bits each).
//   lo2 = c0 + 16*c2, hi2 = c1 + 16*c3;  comb = lo2 | hi2<<8
//   comb*0x1001 = comb + comb<<12 -> bytes [c0+16c2, c1+16(c0+c3), c2+16c1, c3+16c2]
//   (cross terms <= 6<<4: never carry across byte lanes) -> &0x03030303 = [c0,c1,c2,c3]
__device__ __forceinline__ void unpack_word(uint32_t u, uint32_t out[8]) {
  const uint32_t T = 0x42063C00u;
  uint32_t U0 = u & 0x33333333u;
  uint32_t U1 = (u >> 2) & 0x33333333u;
#pragma unroll
  for (int b = 0; b < 4; ++b) {
    uint32_t lo2 = (U0 >> (8 * b)) & 0xFFu;
    uint32_t hi2 = (U1 >> (8 * b)) & 0xFFu;
    uint32_t sel = ((lo2 | (hi2 << 8)) * 0x1001u) & 0x03030303u;
    uint32_t P = __builtin_amdgcn_perm(0u, T, sel);          // [T[c0],T[c1],T[c2],T[c3]]
    out[2 * b]     = __builtin_amdgcn_perm(P, 0u, 0x05000400u); // [0,P0,0,P1] = fp16(c0),fp16(c1)
    out[2 * b + 1] = __builtin_amdgcn_perm(P, 0u, 0x07000600u); // [0,P2,0,P3]
  }
}

// ---- pre-pass: x f32 -> fp16 into workspace (exact, RTZ on representable values) ----
__global__ __launch_bounds__(256)
void cvt_x(const float* __restrict__ x, uint16_t* __restrict__ xh) {
  int i = (blockIdx.x * 256 + threadIdx.x) * 8;   // 4096 blocks * 256 thr * 8 = M*K exactly
  float4 a = *(const float4*)(x + i);
  float4 b = *(const float4*)(x + i + 4);
  uint4 o;
  o.x = cvt2(a.x, a.y); o.y = cvt2(a.z, a.w);
  o.z = cvt2(b.x, b.y); o.w = cvt2(b.z, b.w);
  *(uint4*)(xh + i) = o;
}

// ================= fast path: A via global_load_lds from fp16 workspace =================
__global__ __launch_bounds__(NTHREADS, 2)
void ternary_gemm_ws(const uint16_t* __restrict__ xh,
                     const int*      __restrict__ pw,
                     const float*    __restrict__ bias,
                     float*          __restrict__ out) {
  __shared__ __align__(16) char AsB[BM * A_STRIDE];  // 16 KiB
  __shared__ __align__(16) char BsB[BN * B_STRIDE];  // 18 KiB

  const int tid  = threadIdx.x;
  const int lane = tid & 63;
  const int w    = tid >> 6;
  const int wm   = w >> 1, wn = w & 1;
  const int bid  = blockIdx.x;
  const int bm   = (bid & 7) * BM;    // XCD swizzle: one 2 MiB A-slab per XCD in L2
  const int bn   = (bid >> 3) * BN;

  // A staging: instr q covers rows w*32+q*8 .. +7; lane -> row +(lane>>3), LDS slot lane&7.
  // Slot s of row r holds global 16B chunk c = s ^ (r&7)  (r&7 == lane>>3 here).
  const int ar = lane >> 3;                  // row within 8-row group == row&7
  const int ac = (lane & 7) ^ ar;            // global chunk this lane fetches
  const char* gA[4];
  char*       lA[4];
#pragma unroll
  for (int q = 0; q < 4; ++q) {
    int row = w * 32 + q * 8 + ar;
    gA[q] = (const char*)xh + (size_t)(bm + row) * (K_DIM * 2) + ac * 16;
    lA[q] = AsB + w * 4096 + q * 1024;       // wave-uniform base; HW adds lane*16
  }

  // B staging: thread t -> row t>>1, packed words (t&1)*2..+1 per K-tile
  const int rT = tid >> 1, hT = tid & 1;
  const int2* gB = (const int2*)pw + (size_t)(bn + rT) * (KP / 2) + hT;
  char* dBp[4];
#pragma unroll
  for (int h = 0; h < 4; ++h)
    dBp[h] = BsB + rT * B_STRIDE + (hT * 4 + h) * 16;

  // Fragment offsets (kt-invariant).
  // A: lane holds A[m=lane&15][k=quad*8+j]; stored chunk c at slot c^(row&7), row&7==lane&7.
  int offA[4][2], offB[4][2];
#pragma unroll
  for (int i = 0; i < 4; ++i) {
#pragma unroll
    for (int ks = 0; ks < 2; ++ks) {
      int c = ks * 4 + (lane >> 4);
      int rowA = wm * 64 + i * 16 + (lane & 15);
      offA[i][ks] = rowA * A_STRIDE + ((c ^ (lane & 7)) * 16);
      offB[i][ks] = (wn * 64 + i * 16 + (lane & 15)) * B_STRIDE + c * 16;
    }
  }

  f32x4 acc[4][4];
#pragma unroll
  for (int i = 0; i < 4; ++i)
#pragma unroll
    for (int j = 0; j < 4; ++j)
      acc[i][j] = (f32x4){0.f, 0.f, 0.f, 0.f};

  const int NT = K_DIM / BK;   // 128
  int2 wcur = gB[0];

  for (int kt = 0; kt < NT; ++kt) {
    __syncthreads();           // all waves done reading previous tile's LDS

    // A: async global->LDS (drained by the vmcnt(0) at the next barrier)
#pragma unroll
    for (int q = 0; q < 4; ++q) {
      __builtin_amdgcn_global_load_lds(AS1(gA[q]), AS3(lA[q]), 16, 0, 0);
      gA[q] += BK * 2;
    }

    // B: prefetch next tile's words; decode current -> LDS
    const int kn = (kt + 1 < NT) ? (kt + 1) : kt;
    int2 wnxt = gB[kn * 2];
    uint32_t o0[8], o1[8];
    unpack_word((uint32_t)wcur.x, o0);
    unpack_word((uint32_t)wcur.y, o1);
    *(uint4*)dBp[0] = make_uint4(o0[0], o0[1], o0[2], o0[3]);
    *(uint4*)dBp[1] = make_uint4(o0[4], o0[5], o0[6], o0[7]);
    *(uint4*)dBp[2] = make_uint4(o1[0], o1[1], o1[2], o1[3]);
    *(uint4*)dBp[3] = make_uint4(o1[4], o1[5], o1[6], o1[7]);

    __syncthreads();           // staging visible (vmcnt+lgkmcnt drained)

#pragma unroll
    for (int ks = 0; ks < 2; ++ks) {
      half8 af[4], bf[4];
#pragma unroll
      for (int i = 0; i < 4; ++i) af[i] = *(const half8*)(AsB + offA[i][ks]);
#pragma unroll
      for (int j = 0; j < 4; ++j) bf[j] = *(const half8*)(BsB + offB[j][ks]);
#pragma unroll
      for (int i = 0; i < 4; ++i)
#pragma unroll
        for (int j = 0; j < 4; ++j)
          acc[i][j] = __builtin_amdgcn_mfma_f32_16x16x32_f16(af[i], bf[j], acc[i][j], 0, 0, 0);
    }
    wcur = wnxt;
  }

  // Epilogue: D col(n)=lane&15, row(m)=(lane>>4)*4+reg [m89/m91]; fp16 rounding as reference.
#pragma unroll
  for (int j = 0; j < 4; ++j) {
    int n = bn + wn * 64 + j * 16 + (lane & 15);
    __half hb = __float2half_rn(bias[n]);
#pragma unroll
    for (int i = 0; i < 4; ++i) {
      int m0 = bm + wm * 64 + i * 16 + (lane >> 4) * 4;
#pragma unroll
      for (int r = 0; r < 4; ++r) {
        __half hy = __float2half_rn(acc[i][j][r]);
        out[(size_t)(m0 + r) * N_DIM + n] = __half2float(__hadd(hy, hb));
      }
    }
  }
}

// ================= fallback (R4 kernel, known-good): used only if ws too small =================
__device__ __forceinline__ uint32_t unpack_pair16(uint32_t u, int p) {
  uint32_t c0 = (u >> (4 * p)) & 3u;
  uint32_t c1 = (u >> (4 * p + 2)) & 3u;
  uint32_t lo = (c0 & 1u) * 0x3C00u + (c0 >> 1) * 0x0600u;
  uint32_t hi = (c1 & 1u) * 0x3C00u + (c1 >> 1) * 0x0600u;
  return lo | (hi << 16);
}

__global__ __launch_bounds__(NTHREADS, 2)
void ternary_gemm(const float* __restrict__ x,
                  const int*   __restrict__ pw,
                  const float* __restrict__ bias,
                  float*       __restrict__ out) {
  __shared__ __align__(16) char AsB[BM * B_STRIDE];
  __shared__ __align__(16) char BsB[BN * B_STRIDE];

  const int tid  = threadIdx.x;
  const int lane = tid & 63;
  const int w    = tid >> 6;
  const int wm   = w >> 1, wn = w & 1;
  const int bid  = blockIdx.x;
  const int bm   = (bid & 7) * BM;
  const int bn   = (bid >> 3) * BN;

  const int rT = tid >> 1, hT = tid & 1;
  const float* gA = x + (size_t)(bm + rT) * K_DIM + hT * 32;
  char* const  lA = AsB + rT * B_STRIDE + hT * 64;
  const int2* gB = (const int2*)pw + (size_t)(bn + rT) * (KP / 2) + hT;
  char* dBp[4];
#pragma unroll
  for (int h = 0; h < 4; ++h)
    dBp[h] = BsB + rT * B_STRIDE + (hT * 4 + h) * 16;

  int offA[4][2], offB[4][2];
#pragma unroll
  for (int i = 0; i < 4; ++i)
#pragma unroll
    for (int ks = 0; ks < 2; ++ks) {
      int c = ks * 4 + (lane >> 4);
      offA[i][ks] = (wm * 64 + i * 16 + (lane & 15)) * B_STRIDE + c * 16;
      offB[i][ks] = (wn * 64 + i * 16 + (lane & 15)) * B_STRIDE + c * 16;
    }

  f32x4 acc[4][4];
#pragma unroll
  for (int i = 0; i < 4; ++i)
#pragma unroll
    for (int j = 0; j < 4; ++j)
      acc[i][j] = (f32x4){0.f, 0.f, 0.f, 0.f};

  const int NT = K_DIM / BK;
  for (int kt = 0; kt < NT; ++kt) {
    __syncthreads();
    int2 wcur = gB[kt * 2];
    float4 av[8];
#pragma unroll
    for (int v = 0; v < 8; ++v) av[v] = *(const float4*)(gA + kt * BK + v * 4);
    uint32_t d0[8], d1[8];
#pragma unroll
    for (int p = 0; p < 8; ++p) d0[p] = unpack_pair16((uint32_t)wcur.x, p);
#pragma unroll
    for (int p = 0; p < 8; ++p) d1[p] = unpack_pair16((uint32_t)wcur.y, p);
    *(uint4*)dBp[0] = make_uint4(d0[0], d0[1], d0[2], d0[3]);
    *(uint4*)dBp[1] = make_uint4(d0[4], d0[5], d0[6], d0[7]);
    *(uint4*)dBp[2] = make_uint4(d1[0], d1[1], d1[2], d1[3]);
    *(uint4*)dBp[3] = make_uint4(d1[4], d1[5], d1[6], d1[7]);
#pragma unroll
    for (int v = 0; v < 4; ++v) {
      uint4 aw;
      aw.x = cvt2(av[2 * v].x, av[2 * v].y);
      aw.y = cvt2(av[2 * v].z, av[2 * v].w);
      aw.z = cvt2(av[2 * v + 1].x, av[2 * v + 1].y);
      aw.w = cvt2(av[2 * v + 1].z, av[2 * v + 1].w);
      *(uint4*)(lA + v * 16) = aw;
    }
    __syncthreads();
#pragma unroll
    for (int ks = 0; ks < 2; ++ks) {
      half8 af[4], bf[4];
#pragma unroll
      for (int i = 0; i < 4; ++i) af[i] = *(const half8*)(AsB + offA[i][ks]);
#pragma unroll
      for (int j = 0; j < 4; ++j) bf[j] = *(const half8*)(BsB + offB[j][ks]);
#pragma unroll
      for (int i = 0; i < 4; ++i)
#pragma unroll
        for (int j = 0; j < 4; ++j)
          acc[i][j] = __builtin_amdgcn_mfma_f32_16x16x32_f16(af[i], bf[j], acc[i][j], 0, 0, 0);
    }
  }
#pragma unroll
  for (int j = 0; j < 4; ++j) {
    int n = bn + wn * 64 + j * 16 + (lane & 15);
    __half hb = __float2half_rn(bias[n]);
#pragma unroll
    for (int i = 0; i < 4; ++i) {
      int m0 = bm + wm * 64 + i * 16 + (lane >> 4) * 4;
#pragma unroll
      for (int r = 0; r < 4; ++r) {
        __half hy = __float2half_rn(acc[i][j][r]);
        out[(size_t)(m0 + r) * N_DIM + n] = __half2float(__hadd(hy, hb));
      }
    }
  }
}

extern "C" void kernel_launch(void* const* d_in, const int* in_sizes, int n_in,
                              void* d_out, int out_size, void* d_ws, size_t ws_size,
                              hipStream_t stream) {
  (void)in_sizes; (void)n_in; (void)out_size;
  const float* x    = (const float*)d_in[0];
  const int*   pwp  = (const int*)d_in[1];
  const float* bias = (const float*)d_in[2];
  float*       outp = (float*)d_out;

  const size_t need = (size_t)M_DIM * K_DIM * 2;   // 16 MiB fp16 x
  dim3 grid((M_DIM / BM) * (N_DIM / BN));          // 512 blocks
  if (ws_size >= need) {
    uint16_t* xh = (uint16_t*)d_ws;
    cvt_x<<<(M_DIM * K_DIM) / (256 * 8), 256, 0, stream>>>(x, xh);
    ternary_gemm_ws<<<grid, NTHREADS, 0, stream>>>(xh, pwp, bias, outp);
  } else {
    ternary_gemm<<<grid, NTHREADS, 0, stream>>>(x, pwp, bias, outp);
  }
}